// Round 1
// baseline (408.701 us; speedup 1.0000x reference)
//
#include <hip/hip_runtime.h>
#include <math.h>

// I-BERT IntSoftmax, exact-numerics replication of the JAX reference.
// x: (1,12,2048,2048) f32; 24576 rows of S=2048.
// R4: restructure.
//  - k_scalars eliminated: sym_scale only needs max|x|; k_amax computes it with
//    one atomicMax/block and the LAST block (atomic counter) computes Scalars.
//  - k_row: wave-per-row (64 lanes x 32 elems), barrier-free. Row max of xi is
//    obtained by quantizing the raw row max (quantization chain is monotone
//    non-decreasing => max commutes, bit-exact). Single fused pass per element.

#define ROW_S 2048
#define MM_BLOCKS 2048

typedef float floatx4 __attribute__((ext_vector_type(4)));

struct Scalars {
    double exp_sf_d;   // exp_sf (f64) — fixedpoint_mul divisor
    double inv_exp_sf; // RN(1/exp_sf_d), f64 (Markstein reciprocal)
    double m_int;      // 31-bit mantissa (f64)
    double inv_pow;    // 2^(e-31) exact
    float  sf;         // activation scale
    float  inv_sf;     // RN(1/sf)
    float  x0_int;     // floor(-0.6931/sf)
    float  inv_x0;     // RN(1/x0_int)
    float  b_int;      // floor(COEF1/sf)
    float  c_int;      // floor(COEF2/sf^2)
    float  thirty_x0;  // 30 * x0_int (exact)
    float  _pad;
};

// Markstein: with inv = RN(1/b), returns RN(a/b) bit-exactly.
__device__ __forceinline__ float div_rn(float a, float b, float inv) {
    const float q0 = __fmul_rn(a, inv);
    const float r  = __fmaf_rn(-b, q0, a);
    return __fmaf_rn(r, inv, q0);
}
__device__ __forceinline__ double ddiv_rn(double a, double b, double inv) {
    const double q0 = __dmul_rn(a, inv);
    const double r  = __fma_rn(-b, q0, a);
    return __fma_rn(r, inv, q0);
}

// Pass 1: global max|x| (grid-stride), + last-block-done computes Scalars.
// amax_bits/counter must be zeroed before launch (hipMemsetAsync).
__global__ __launch_bounds__(256) void k_amax(const float* __restrict__ x,
                                              unsigned* __restrict__ amax_bits,
                                              unsigned* __restrict__ counter,
                                              Scalars* __restrict__ sc,
                                              int n4) {
    const int tid = threadIdx.x;
    float am = 0.0f;
    const float4* x4 = (const float4*)x;
    for (int i = blockIdx.x * 256 + tid; i < n4; i += MM_BLOCKS * 256) {
        float4 v = x4[i];
        am = fmaxf(am, fabsf(v.x));
        am = fmaxf(am, fabsf(v.y));
        am = fmaxf(am, fabsf(v.z));
        am = fmaxf(am, fabsf(v.w));
    }
#pragma unroll
    for (int m = 32; m > 0; m >>= 1) am = fmaxf(am, __shfl_xor(am, m));
    __shared__ float sred[4];
    const int wave = tid >> 6, lane = tid & 63;
    if (lane == 0) sred[wave] = am;
    __syncthreads();
    if (tid == 0) {
        const float ba = fmaxf(fmaxf(sred[0], sred[1]), fmaxf(sred[2], sred[3]));
        // |x| >= 0: raw float bits are order-isomorphic to uint; init 0 ok.
        atomicMax(amax_bits, __float_as_uint(ba));
        __threadfence();
        const unsigned old = atomicAdd(counter, 1u);
        if (old == MM_BLOCKS - 1) {
            // all blocks' atomicMax precede their fences precede their adds:
            // amax is final here.
            const float sabs = __uint_as_float(atomicMax(amax_bits, 0u));
            // sym_scale(x.min, x.max, 16) == sym_scale via max|x|, all f32
            const float sf    = __fdiv_rn(fmaxf(sabs, 1e-8f), 32767.0f);
            const float x0i   = floorf(__fdiv_rn((float)(-0.6931), sf));
            const float sfsq  = __fmul_rn(sf, sf);
            const float b_int = floorf(__fdiv_rn((float)(0.96963238 / 0.35815147), sf));
            const float c_int = floorf(__fdiv_rn((float)(1.0 / 0.35815147), sfsq));
            const float exp_sf = __fdiv_rn(__fmul_rn((float)(0.35815147), sfsq), 1073741824.0f);
            // global max of exp_int is exactly c_int * 2^30 (row-max element:
            // r=0,q=0 => z=c_int); min>=0, so sym_scale uses this max.
            const float emax   = __fmul_rn(c_int, 1073741824.0f);
            const float act_sf = __fdiv_rn(fmaxf(emax, 1e-8f), 32767.0f);
            // fixedpoint_mul scalar part (f64, per reference)
            const float  nsf = __fdiv_rn(exp_sf, act_sf);
            const double ns  = (double)nsf;
            int E;
            (void)frexp(ns, &E);                 // e = floor(log2(ns)) + 1 == E
            const double m_int = rint(ldexp(ns, 31 - E));
            sc->exp_sf_d   = (double)exp_sf;
            sc->inv_exp_sf = 1.0 / (double)exp_sf;
            sc->m_int      = m_int;
            sc->inv_pow    = ldexp(1.0, E - 31);          // exact pow2
            sc->sf         = sf;
            sc->inv_sf     = __fdiv_rn(1.0f, sf);
            sc->x0_int     = x0i;
            sc->inv_x0     = __fdiv_rn(1.0f, x0i);
            sc->b_int      = b_int;
            sc->c_int      = c_int;
            sc->thirty_x0  = __fmul_rn(30.0f, x0i);       // exact (int < 2^24)
        }
    }
}

// Pass 2: one wave per row, 32 elements/lane, no LDS, no __syncthreads.
__global__ __launch_bounds__(256) void k_row(const float* __restrict__ x,
                                             float* __restrict__ out,
                                             const Scalars* __restrict__ scp) {
    const int lane = threadIdx.x & 63;
    const int wave = threadIdx.x >> 6;
    const size_t row = (size_t)blockIdx.x * 4 + wave;
    const floatx4* x4 = (const floatx4*)(x + row * ROW_S);
    floatx4* o4 = (floatx4*)(out + row * ROW_S);

    // issue all global loads first; scalar struct load overlaps
    floatx4 v[8];
#pragma unroll
    for (int i = 0; i < 8; ++i) v[i] = x4[i * 64 + lane];

    const Scalars sc = *scp;
    const float sf = sc.sf, inv_sf = sc.inv_sf;

    // raw row max (quant chain is monotone => ximax = quant(raw max), exact)
    float rmax = -INFINITY;
#pragma unroll
    for (int i = 0; i < 8; ++i) {
#pragma unroll
        for (int c = 0; c < 4; ++c) rmax = fmaxf(rmax, v[i][c]);
    }
#pragma unroll
    for (int m = 32; m > 0; m >>= 1) rmax = fmaxf(rmax, __shfl_xor(rmax, m));

    float t = rintf(div_rn(rmax, sf, inv_sf));
    t = fminf(fmaxf(t, -32768.0f), 32767.0f);
    t = __fmul_rn(t, sf);
    const float ximax = div_rn(t, sf, inv_sf);

    float ssum = 0.0f;
#pragma unroll
    for (int i = 0; i < 8; ++i) {
#pragma unroll
        for (int c = 0; c < 4; ++c) {
            // QuantAct(16): x_int = clip(rint(x/sf)); xi = (x_int*sf)/sf (RN, no FMA)
            float q = rintf(div_rn(v[i][c], sf, inv_sf));
            q = fminf(fmaxf(q, -32768.0f), 32767.0f);
            q = __fmul_rn(q, sf);
            const float xi = div_rn(q, sf, inv_sf);
            const float xs = __fsub_rn(xi, ximax);
            const float xm = fmaxf(xs, sc.thirty_x0);
            const float qf = floorf(div_rn(xm, sc.x0_int, sc.inv_x0));
            const float r  = __fsub_rn(xm, __fmul_rn(sc.x0_int, qf));
            // z = r*(r+b)+c — must NOT contract to FMA (XLA CPU doesn't)
            const float z  = __fadd_rn(__fmul_rn(r, __fadd_rn(r, sc.b_int)), sc.c_int);
            const int   qi = (int)qf;                          // qf in [0,30]
            const float p2 = __int_as_float((157 - qi) << 23); // exactly 2^(30-qi)
            const float ei = fmaxf(floorf(__fmul_rn(z, p2)), 0.0f);
            // fixedpoint_mul in f64 (reference runs in double)
            const double a  = (double)ei;
            const double zi = rint(ddiv_rn(a, sc.exp_sf_d, sc.inv_exp_sf));
            double ovd = rint(__dmul_rn(__dmul_rn(zi, sc.m_int), sc.inv_pow));
            ovd = fmin(fmax(ovd, -32768.0), 32767.0);
            const float e16 = (float)ovd;   // integer-valued, exact
            v[i][c] = e16;
            ssum += e16;   // non-negative ints, row sum < 2^24 -> order-free exact
        }
    }
#pragma unroll
    for (int m = 32; m > 0; m >>= 1) ssum += __shfl_xor(ssum, m);
    const float factor = floorf(__fdiv_rn(4294967296.0f, ssum));

#pragma unroll
    for (int i = 0; i < 8; ++i) {
        floatx4 w;
#pragma unroll
        for (int c = 0; c < 4; ++c) {
            // /2^24 == *2^-24 exactly (pow2), then *2^-8 exact
            const float oi = floorf(__fmul_rn(__fmul_rn(v[i][c], factor), 5.9604644775390625e-8f));
            w[c] = __fmul_rn(oi, 0.00390625f);
        }
        __builtin_nontemporal_store(w, &o4[i * 64 + lane]);
    }
}

extern "C" void kernel_launch(void* const* d_in, const int* in_sizes, int n_in,
                              void* d_out, int out_size, void* d_ws, size_t ws_size,
                              hipStream_t stream) {
    const float* x = (const float*)d_in[0];
    float* out = (float*)d_out;
    const int n = in_sizes[0];          // 50331648
    const int rows = n / ROW_S;         // 24576

    unsigned* amax_bits = (unsigned*)d_ws;        // [0,4): max|x| as uint key
    unsigned* counter   = amax_bits + 1;          // [4,8): blocks-done counter
    Scalars*  sc        = (Scalars*)((char*)d_ws + 64);

    hipMemsetAsync(d_ws, 0, 8, stream);           // zero amax key + counter
    k_amax<<<MM_BLOCKS, 256, 0, stream>>>(x, amax_bits, counter, sc, n / 4);
    k_row<<<rows / 4, 256, 0, stream>>>(x, out, sc);
}

// Round 2
// 357.812 us; speedup vs baseline: 1.1422x; 1.1422x over previous
//
#include <hip/hip_runtime.h>
#include <math.h>

// I-BERT IntSoftmax, exact-numerics replication of the JAX reference.
// x: (1,12,2048,2048) f32; 24576 rows of S=2048.
// R5: revert R4's fused atomic reduction (2048 same-line atomicMax+fence+add
//     serialized cross-XCD => k_amax 128us @ 775 GB/s). Back to contention-free
//     per-block partials + tiny k_scalars. k_row (wave-per-row, ~35us) kept.

#define ROW_S 2048
#define MM_BLOCKS 2048
#define MM_STRIDE (MM_BLOCKS * 256)

typedef float floatx4 __attribute__((ext_vector_type(4)));

struct Scalars {
    double exp_sf_d;   // exp_sf (f64) — fixedpoint_mul divisor
    double inv_exp_sf; // RN(1/exp_sf_d), f64 (Markstein reciprocal)
    double m_int;      // 31-bit mantissa (f64)
    double inv_pow;    // 2^(e-31) exact
    float  sf;         // activation scale
    float  inv_sf;     // RN(1/sf)
    float  x0_int;     // floor(-0.6931/sf)
    float  inv_x0;     // RN(1/x0_int)
    float  b_int;      // floor(COEF1/sf)
    float  c_int;      // floor(COEF2/sf^2)
    float  thirty_x0;  // 30 * x0_int (exact)
    float  _pad;
};

// Markstein: with inv = RN(1/b), returns RN(a/b) bit-exactly.
__device__ __forceinline__ float div_rn(float a, float b, float inv) {
    const float q0 = __fmul_rn(a, inv);
    const float r  = __fmaf_rn(-b, q0, a);
    return __fmaf_rn(r, inv, q0);
}
__device__ __forceinline__ double ddiv_rn(double a, double b, double inv) {
    const double q0 = __dmul_rn(a, inv);
    const double r  = __fma_rn(-b, q0, a);
    return __fma_rn(r, inv, q0);
}

// Pass 1: per-block partial max|x| -> pmax[bid]. Plain store, NO atomics/fences.
__global__ __launch_bounds__(256) void k_amax(const float* __restrict__ x,
                                              float* __restrict__ pmax,
                                              int n4) {
    const int tid = threadIdx.x;
    const float4* x4 = (const float4*)x;
    float am = 0.0f;
    int i = blockIdx.x * 256 + tid;
    // 4x unrolled grid-stride: 4 independent loads in flight per wave (MLP)
    for (; i + 3 * MM_STRIDE < n4; i += 4 * MM_STRIDE) {
        const float4 v0 = x4[i];
        const float4 v1 = x4[i + MM_STRIDE];
        const float4 v2 = x4[i + 2 * MM_STRIDE];
        const float4 v3 = x4[i + 3 * MM_STRIDE];
        const float m0 = fmaxf(fmaxf(fabsf(v0.x), fabsf(v0.y)), fmaxf(fabsf(v0.z), fabsf(v0.w)));
        const float m1 = fmaxf(fmaxf(fabsf(v1.x), fabsf(v1.y)), fmaxf(fabsf(v1.z), fabsf(v1.w)));
        const float m2 = fmaxf(fmaxf(fabsf(v2.x), fabsf(v2.y)), fmaxf(fabsf(v2.z), fabsf(v2.w)));
        const float m3 = fmaxf(fmaxf(fabsf(v3.x), fabsf(v3.y)), fmaxf(fabsf(v3.z), fabsf(v3.w)));
        am = fmaxf(am, fmaxf(fmaxf(m0, m1), fmaxf(m2, m3)));
    }
    for (; i < n4; i += MM_STRIDE) {
        const float4 v = x4[i];
        am = fmaxf(am, fmaxf(fmaxf(fabsf(v.x), fabsf(v.y)), fmaxf(fabsf(v.z), fabsf(v.w))));
    }
#pragma unroll
    for (int m = 32; m > 0; m >>= 1) am = fmaxf(am, __shfl_xor(am, m));
    __shared__ float sred[4];
    const int wave = tid >> 6, lane = tid & 63;
    if (lane == 0) sred[wave] = am;
    __syncthreads();
    if (tid == 0)
        pmax[blockIdx.x] = fmaxf(fmaxf(sred[0], sred[1]), fmaxf(sred[2], sred[3]));
}

// Pass 1b: single block reduces 2048 partials and derives all Scalars.
__global__ __launch_bounds__(256) void k_scalars(const float* __restrict__ pmax,
                                                 Scalars* __restrict__ sc) {
    const int tid = threadIdx.x;
    float am = 0.0f;
    for (int i = tid; i < MM_BLOCKS; i += 256) am = fmaxf(am, pmax[i]);
#pragma unroll
    for (int m = 32; m > 0; m >>= 1) am = fmaxf(am, __shfl_xor(am, m));
    __shared__ float sred[4];
    const int wave = tid >> 6, lane = tid & 63;
    if (lane == 0) sred[wave] = am;
    __syncthreads();
    if (tid == 0) {
        const float sabs = fmaxf(fmaxf(sred[0], sred[1]), fmaxf(sred[2], sred[3]));
        // sym_scale(x.min, x.max, 16) via max|x|, all f32 like the reference
        const float sf    = __fdiv_rn(fmaxf(sabs, 1e-8f), 32767.0f);
        const float x0i   = floorf(__fdiv_rn((float)(-0.6931), sf));
        const float sfsq  = __fmul_rn(sf, sf);
        const float b_int = floorf(__fdiv_rn((float)(0.96963238 / 0.35815147), sf));
        const float c_int = floorf(__fdiv_rn((float)(1.0 / 0.35815147), sfsq));
        const float exp_sf = __fdiv_rn(__fmul_rn((float)(0.35815147), sfsq), 1073741824.0f);
        // global max of exp_int is exactly c_int * 2^30 (row-max element:
        // r=0,q=0 => z=c_int); min>=0, so sym_scale uses this max.
        const float emax   = __fmul_rn(c_int, 1073741824.0f);
        const float act_sf = __fdiv_rn(fmaxf(emax, 1e-8f), 32767.0f);
        // fixedpoint_mul scalar part (f64, per reference)
        const float  nsf = __fdiv_rn(exp_sf, act_sf);
        const double ns  = (double)nsf;
        int E;
        (void)frexp(ns, &E);                 // e = floor(log2(ns)) + 1 == E
        const double m_int = rint(ldexp(ns, 31 - E));
        sc->exp_sf_d   = (double)exp_sf;
        sc->inv_exp_sf = 1.0 / (double)exp_sf;
        sc->m_int      = m_int;
        sc->inv_pow    = ldexp(1.0, E - 31);          // exact pow2
        sc->sf         = sf;
        sc->inv_sf     = __fdiv_rn(1.0f, sf);
        sc->x0_int     = x0i;
        sc->inv_x0     = __fdiv_rn(1.0f, x0i);
        sc->b_int      = b_int;
        sc->c_int      = c_int;
        sc->thirty_x0  = __fmul_rn(30.0f, x0i);       // exact (int < 2^24)
    }
}

// Pass 2: one wave per row, 32 elements/lane, no LDS, no __syncthreads.
__global__ __launch_bounds__(256) void k_row(const float* __restrict__ x,
                                             float* __restrict__ out,
                                             const Scalars* __restrict__ scp) {
    const int lane = threadIdx.x & 63;
    const int wave = threadIdx.x >> 6;
    const size_t row = (size_t)blockIdx.x * 4 + wave;
    const floatx4* x4 = (const floatx4*)(x + row * ROW_S);
    floatx4* o4 = (floatx4*)(out + row * ROW_S);

    // issue all global loads first; scalar struct load overlaps
    floatx4 v[8];
#pragma unroll
    for (int i = 0; i < 8; ++i) v[i] = x4[i * 64 + lane];

    const Scalars sc = *scp;
    const float sf = sc.sf, inv_sf = sc.inv_sf;

    // raw row max (quant chain is monotone => ximax = quant(raw max), exact)
    float rmax = -INFINITY;
#pragma unroll
    for (int i = 0; i < 8; ++i) {
#pragma unroll
        for (int c = 0; c < 4; ++c) rmax = fmaxf(rmax, v[i][c]);
    }
#pragma unroll
    for (int m = 32; m > 0; m >>= 1) rmax = fmaxf(rmax, __shfl_xor(rmax, m));

    float t = rintf(div_rn(rmax, sf, inv_sf));
    t = fminf(fmaxf(t, -32768.0f), 32767.0f);
    t = __fmul_rn(t, sf);
    const float ximax = div_rn(t, sf, inv_sf);

    float ssum = 0.0f;
#pragma unroll
    for (int i = 0; i < 8; ++i) {
#pragma unroll
        for (int c = 0; c < 4; ++c) {
            // QuantAct(16): x_int = clip(rint(x/sf)); xi = (x_int*sf)/sf (RN, no FMA)
            float q = rintf(div_rn(v[i][c], sf, inv_sf));
            q = fminf(fmaxf(q, -32768.0f), 32767.0f);
            q = __fmul_rn(q, sf);
            const float xi = div_rn(q, sf, inv_sf);
            const float xs = __fsub_rn(xi, ximax);
            const float xm = fmaxf(xs, sc.thirty_x0);
            const float qf = floorf(div_rn(xm, sc.x0_int, sc.inv_x0));
            const float r  = __fsub_rn(xm, __fmul_rn(sc.x0_int, qf));
            // z = r*(r+b)+c — must NOT contract to FMA (XLA CPU doesn't)
            const float z  = __fadd_rn(__fmul_rn(r, __fadd_rn(r, sc.b_int)), sc.c_int);
            const int   qi = (int)qf;                          // qf in [0,30]
            const float p2 = __int_as_float((157 - qi) << 23); // exactly 2^(30-qi)
            const float ei = fmaxf(floorf(__fmul_rn(z, p2)), 0.0f);
            // fixedpoint_mul in f64 (reference runs in double)
            const double a  = (double)ei;
            const double zi = rint(ddiv_rn(a, sc.exp_sf_d, sc.inv_exp_sf));
            double ovd = rint(__dmul_rn(__dmul_rn(zi, sc.m_int), sc.inv_pow));
            ovd = fmin(fmax(ovd, -32768.0), 32767.0);
            const float e16 = (float)ovd;   // integer-valued, exact
            v[i][c] = e16;
            ssum += e16;   // non-negative ints, row sum < 2^24 -> order-free exact
        }
    }
#pragma unroll
    for (int m = 32; m > 0; m >>= 1) ssum += __shfl_xor(ssum, m);
    const float factor = floorf(__fdiv_rn(4294967296.0f, ssum));

#pragma unroll
    for (int i = 0; i < 8; ++i) {
        floatx4 w;
#pragma unroll
        for (int c = 0; c < 4; ++c) {
            // /2^24 == *2^-24 exactly (pow2), then *2^-8 exact
            const float oi = floorf(__fmul_rn(__fmul_rn(v[i][c], factor), 5.9604644775390625e-8f));
            w[c] = __fmul_rn(oi, 0.00390625f);
        }
        __builtin_nontemporal_store(w, &o4[i * 64 + lane]);
    }
}

extern "C" void kernel_launch(void* const* d_in, const int* in_sizes, int n_in,
                              void* d_out, int out_size, void* d_ws, size_t ws_size,
                              hipStream_t stream) {
    const float* x = (const float*)d_in[0];
    float* out = (float*)d_out;
    const int n = in_sizes[0];          // 50331648
    const int rows = n / ROW_S;         // 24576

    Scalars* sc = (Scalars*)d_ws;
    float* pmax = (float*)((char*)d_ws + 256);

    k_amax<<<MM_BLOCKS, 256, 0, stream>>>(x, pmax, n / 4);
    k_scalars<<<1, 256, 0, stream>>>(pmax, sc);
    k_row<<<rows / 4, 256, 0, stream>>>(x, out, sc);
}